// Round 3
// baseline (75.339 us; speedup 1.0000x reference)
//
#include <hip/hip_runtime.h>
#include <stdint.h>

// Problem constants (from reference)
#define BATCH 1024
#define FEAT  784
#define OUTF  1024
#define OR_T  32
#define AND_T 16
#define NIDX  1569          // 1 + 2*FEAT boolean input columns
#define LWORDS 1600         // padded LDS words for the bit table

typedef unsigned long long u64;

// ---------------------------------------------------------------------------
// Fused kernel: pack 64 batch rows into bit columns (LDS), then evaluate the
// OR-of-ANDs with bit-parallel u64 ops.
//
// grid  = (16 batch-groups, 16 output-chunks), block = 1024 (16 waves/CU).
// Pack: each wave covers a contiguous slice of the 196 float4 feature chunks;
//       __ballot across the 64 lanes (= 64 batch rows) builds each column.
// Eval: thread (tg, o_local) = tid(hi,lo) handles 2 OR-terms of output
//       ob*64+o_local -> 32 ds_read_b64 gathers; OR-reduce 16 partials via
//       LDS; each thread stores 4 batch rows (coalesced across o_local).
// Output dtype int32 (reference returns bool -> harness reads np.int32).
// ---------------------------------------------------------------------------
__global__ __launch_bounds__(1024) void binlayer(const float* __restrict__ x,
                                                 const int* __restrict__ w,
                                                 int* __restrict__ out) {
    __shared__ u64 lbits[LWORDS];
    __shared__ u64 red[1024];

    const int g    = blockIdx.x;
    const int ob   = blockIdx.y;
    const int tid  = threadIdx.x;
    const int lane = tid & 63;
    const int wv   = tid >> 6;            // wave id 0..15

    // ---- pack phase: 196 float4 chunks split 13/13/13/13/12*12 over 16 waves
    const int start = wv * 12 + (wv < 4 ? wv : 4);
    const int cnt   = (wv < 4) ? 13 : 12;
    const float4* xrow = (const float4*)(x + (size_t)(g * 64 + lane) * FEAT);
    for (int i = 0; i < cnt; ++i) {
        const int f4 = start + i;
        const float4 v = xrow[f4];
        const int f = f4 * 4;
        const u64 m0 = __ballot(v.x != 0.0f);
        const u64 m1 = __ballot(v.y != 0.0f);
        const u64 m2 = __ballot(v.z != 0.0f);
        const u64 m3 = __ballot(v.w != 0.0f);
        const u64 mv = (lane == 0) ? m0 : (lane == 1) ? m1 : (lane == 2) ? m2 : m3;
        if (lane < 4) {
            lbits[1 + f + lane]   = mv;
            lbits[785 + f + lane] = ~mv;
        }
    }
    if (tid == 0) lbits[0] = ~0ull;
    __syncthreads();

    // ---- eval phase: 2 OR-terms per thread
    const int o_local = tid & 63;
    const int tg      = tid >> 6;         // term-group 0..15
    const int o       = ob * 64 + o_local;

    // terms tg*2, tg*2+1 of output o; each term's 16 indices = one 64B line
    const int4* wq = (const int4*)(w + ((size_t)o * OR_T + tg * 2) * AND_T);

    u64 orv = 0;
    #pragma unroll
    for (int tt = 0; tt < 2; ++tt) {
        u64 a = ~0ull;
        int zor = 0;                      // OR of the 16 indices (or_mask)
        #pragma unroll
        for (int k = 0; k < 4; ++k) {
            const int4 wi = wq[tt * 4 + k];
            zor |= wi.x | wi.y | wi.z | wi.w;
            a &= lbits[wi.x];
            a &= lbits[wi.y];
            a &= lbits[wi.z];
            a &= lbits[wi.w];
        }
        if (zor != 0) orv |= a;           // all-zero term is masked off
    }

    red[tid] = orv;
    __syncthreads();

    // OR across the 16 term-groups (bank-minimal: lanes span all 32 banks)
    u64 full = 0;
    #pragma unroll
    for (int j = 0; j < 16; ++j) full |= red[o_local + j * 64];

    // each thread writes 4 batch rows; o_local in lane bits -> 256B coalesced
    int* outg = out + (size_t)(g * 64) * OUTF + (size_t)ob * 64;
    #pragma unroll
    for (int jj = 0; jj < 4; ++jj) {
        const int j = tg * 4 + jj;
        outg[(size_t)j * OUTF + o_local] = (int)((full >> j) & 1);
    }
}

extern "C" void kernel_launch(void* const* d_in, const int* in_sizes, int n_in,
                              void* d_out, int out_size, void* d_ws, size_t ws_size,
                              hipStream_t stream) {
    const float* x = (const float*)d_in[0];   // (1024, 784) float32 of 0/1
    const int*   w = (const int*)d_in[1];     // (1024, 32, 16) int32 in [0,1569)
    int* out = (int*)d_out;                   // (1024, 1024) bool -> int32

    binlayer<<<dim3(BATCH / 64, OUTF / 64), 1024, 0, stream>>>(x, w, out);
}